// Round 19
// baseline (153.834 us; speedup 1.0000x reference)
//
#include <hip/hip_runtime.h>
#include <hip/hip_fp16.h>
#include <math.h>

#define T_DIM 2048
#define D_DIM 2048
#define NHEAD 16
#define DHEAD 128

typedef _Float16 h8 __attribute__((ext_vector_type(8)));   // 8 fp16 (4 VGPRs)
typedef float v4f __attribute__((ext_vector_type(4)));
typedef unsigned short ush;

#define MFMAH(a, b, c) __builtin_amdgcn_mfma_f32_16x16x32_f16((a), (b), (c), 0, 0, 0)

__device__ __forceinline__ ush f2h(float f) {
    return __half_as_ushort(__float2half(f));   // RTN
}
__device__ __forceinline__ unsigned pack2(ush a, ush b) {
    return (unsigned)a | ((unsigned)b << 16);
}
__device__ __forceinline__ unsigned pkrtz(float a, float b) {   // v_cvt_pkrtz_f16_f32
    auto r = __builtin_amdgcn_cvt_pkrtz(a, b);  // __fp16 ext_vector_type(2)
    return __builtin_bit_cast(unsigned, r);
}

__device__ __forceinline__ void gload_lds16(const ush* g, ush* l) {
    __builtin_amdgcn_global_load_lds(
        (const __attribute__((address_space(1))) void*)g,
        (__attribute__((address_space(3))) void*)l, 16, 0, 0);
}

// 2-D region XCD swizzle for a 32(m) x 32(n) grid of 1024 blocks (64x64
// tiles). 8 XCDs as 2 rows x 4 cols; each XCD owns a 16m x 8n region of 128
// blocks (m fastest within region -> B panel shared by 16 consecutive
// blocks, A slice L2-resident). r9 precedent: region swizzle cut FETCH 2.8x.
__device__ __forceinline__ void region_swizzle64(int bid, int& m0, int& n0) {
    const int xcd = bid & 7;
    const int lg  = bid >> 3;                        // 0..127
    const int mp  = ((xcd >> 2) << 4) + (lg & 15);   // 0..31
    const int np  = ((xcd & 3) << 3) + (lg >> 4);    // 0..31
    m0 = mp * 64;
    n0 = np * 64;
}

// ---------------------------------------------------------------------------
// Fused 5-matrix fp32 -> fp16 cast (x, Wq, Wk, Wv, Wo).
// ---------------------------------------------------------------------------
struct Cvt5Args { const float* s[5]; ush* d[5]; };

__global__ __launch_bounds__(256) void cvt5(Cvt5Args a)
{
    const int m = blockIdx.y;
    const float* X = a.s[m];
    ush* Dst = a.d[m];
    const int i = (blockIdx.x * 256 + threadIdx.x) * 8;
    const float4 p = *(const float4*)&X[i];
    const float4 q = *(const float4*)&X[i + 4];
    uint4 o;
    o.x = pack2(f2h(p.x), f2h(p.y));
    o.y = pack2(f2h(p.z), f2h(p.w));
    o.z = pack2(f2h(q.x), f2h(q.y));
    o.w = pack2(f2h(q.z), f2h(q.w));
    *(uint4*)&Dst[i] = o;
}

// ---------------------------------------------------------------------------
// FUSED QKV GEMM, plain fp16. Round-19: 64x64 tiles -> grid 1024 -> 4
// blocks/CU resident (was 512 blocks = 2/CU, grid-limited; Occupancy 18%).
// 256 threads = 4 waves (2m x 2n), wave-tile 32x32. LDS: A[64][64] 8KB +
// 3x B[64][64] 24KB = 32KB. Same conflict-free XOR row geometry, same
// K-accumulation order per output (bit-identical results).
// ---------------------------------------------------------------------------
__global__ __launch_bounds__(256, 4) void gemm_qkv_f16(
    const ush* __restrict__ xf,
    const ush* __restrict__ Wqf, const ush* __restrict__ Wkf,
    const ush* __restrict__ Wvf,
    const float* __restrict__ bq, const float* __restrict__ bk,
    const float* __restrict__ bv, float qscale,
    ush* __restrict__ Qo, ush* __restrict__ Ko, ush* __restrict__ Vto)
{
    __shared__ ush As[64 * 64];
    __shared__ ush Bs[3][64 * 64];

    const int tid = threadIdx.x;
    const int l   = tid & 63;
    const int wid = tid >> 6;      // 0..3
    const int wm  = wid >> 1;      // 0..1 (m half)
    const int wn  = wid & 1;       // 0..1 (n half)
    const int cl  = l & 15;
    const int rg  = l >> 4;

    int m0, n0;
    region_swizzle64(blockIdx.x, m0, n0);

    const ush* Wf[3] = {Wqf, Wkf, Wvf};

    v4f acc[3][2][2];
#pragma unroll
    for (int wg = 0; wg < 3; ++wg)
#pragma unroll
        for (int mf = 0; mf < 2; ++mf)
#pragma unroll
            for (int nf = 0; nf < 2; ++nf) acc[wg][mf][nf] = (v4f)0.f;

    for (int ks = 0; ks < D_DIM / 64; ++ks) {
        const int k0 = ks * 64;
        __syncthreads();
        // A: 64 rows x 8 chunks = 512 slots, 2 per thread
#pragma unroll
        for (int i = 0; i < 2; ++i) {
            const int p   = i * 256 + tid;
            const int row = p >> 3;
            const int lc  = (p & 7) ^ (row & 7);
            gload_lds16(&xf[(size_t)(m0 + row) * D_DIM + k0 + lc * 8], &As[p * 8]);
        }
        // B: 512 slots per weight, 2 per thread each
#pragma unroll
        for (int i = 0; i < 2; ++i) {
            const int p   = i * 256 + tid;
            const int row = p >> 3;
            const int lc  = (p & 7) ^ (row & 7);
            const size_t off = (size_t)(n0 + row) * D_DIM + k0 + lc * 8;
#pragma unroll
            for (int wg = 0; wg < 3; ++wg)
                gload_lds16(&Wf[wg][off], &Bs[wg][p * 8]);
        }
        __syncthreads();

#pragma unroll
        for (int kf = 0; kf < 2; ++kf) {
            const int c = kf * 4 + rg;
            h8 a[2];
#pragma unroll
            for (int mf = 0; mf < 2; ++mf) {
                const int r = wm * 32 + mf * 16 + cl;
                a[mf] = *(const h8*)&As[r * 64 + ((c ^ (r & 7)) * 8)];
            }
#pragma unroll
            for (int wg = 0; wg < 3; ++wg) {
                h8 b[2];
#pragma unroll
                for (int nf = 0; nf < 2; ++nf) {
                    const int r = wn * 32 + nf * 16 + cl;
                    b[nf] = *(const h8*)&Bs[wg][r * 64 + ((c ^ (r & 7)) * 8)];
                }
#pragma unroll
                for (int mf = 0; mf < 2; ++mf)
#pragma unroll
                    for (int nf = 0; nf < 2; ++nf)
                        acc[wg][mf][nf] = MFMAH(a[mf], b[nf], acc[wg][mf][nf]);
            }
        }
    }

#pragma unroll
    for (int mf = 0; mf < 2; ++mf)
#pragma unroll
        for (int nf = 0; nf < 2; ++nf) {
            const int n  = n0 + wn * 32 + nf * 16 + cl;
            const int mb = m0 + wm * 32 + mf * 16 + rg * 4;
            const float bvq = bq[n], bvk = bk[n], bvv = bv[n];
#pragma unroll
            for (int j = 0; j < 4; ++j) {
                Qo[(size_t)(mb + j) * D_DIM + n] =
                    f2h((acc[0][mf][nf][j] + bvq) * qscale);
                Ko[(size_t)(mb + j) * D_DIM + n] =
                    f2h(acc[1][mf][nf][j] + bvk);
            }
            ushort4 pk;
            pk.x = f2h(acc[2][mf][nf][0] + bvv);
            pk.y = f2h(acc[2][mf][nf][1] + bvv);
            pk.z = f2h(acc[2][mf][nf][2] + bvv);
            pk.w = f2h(acc[2][mf][nf][3] + bvv);
            *(ushort4*)&Vto[(size_t)n * D_DIM + mb] = pk;   // Vt[n][m..m+3]
        }
}

// ---------------------------------------------------------------------------
// O-projection GEMM, plain fp16. Round-19: 64x64 tiles -> 1024 blocks ->
// 4 blocks/CU (16 KB LDS).
// ---------------------------------------------------------------------------
__global__ __launch_bounds__(256, 4) void gemm_o_f16(
    const ush* __restrict__ Yf, const ush* __restrict__ Wof,
    const float* __restrict__ bo, float* __restrict__ out)
{
    __shared__ ush As[64 * 64];
    __shared__ ush Bs[64 * 64];

    const int tid = threadIdx.x;
    const int l   = tid & 63;
    const int wid = tid >> 6;
    const int wm  = wid >> 1;
    const int wn  = wid & 1;
    const int cl  = l & 15;
    const int rg  = l >> 4;

    int m0, n0;
    region_swizzle64(blockIdx.x, m0, n0);

    v4f acc[2][2];
#pragma unroll
    for (int mf = 0; mf < 2; ++mf)
#pragma unroll
        for (int nf = 0; nf < 2; ++nf) acc[mf][nf] = (v4f)0.f;

    for (int ks = 0; ks < D_DIM / 64; ++ks) {
        const int k0 = ks * 64;
        __syncthreads();
#pragma unroll
        for (int i = 0; i < 2; ++i) {
            const int p   = i * 256 + tid;
            const int row = p >> 3;
            const int lc  = (p & 7) ^ (row & 7);
            gload_lds16(&Yf[(size_t)(m0 + row) * D_DIM + k0 + lc * 8], &As[p * 8]);
        }
#pragma unroll
        for (int i = 0; i < 2; ++i) {
            const int p   = i * 256 + tid;
            const int row = p >> 3;
            const int lc  = (p & 7) ^ (row & 7);
            gload_lds16(&Wof[(size_t)(n0 + row) * D_DIM + k0 + lc * 8], &Bs[p * 8]);
        }
        __syncthreads();

#pragma unroll
        for (int kf = 0; kf < 2; ++kf) {
            const int c = kf * 4 + rg;
            h8 a[2], b[2];
#pragma unroll
            for (int mf = 0; mf < 2; ++mf) {
                const int r = wm * 32 + mf * 16 + cl;
                a[mf] = *(const h8*)&As[r * 64 + ((c ^ (r & 7)) * 8)];
            }
#pragma unroll
            for (int nf = 0; nf < 2; ++nf) {
                const int r = wn * 32 + nf * 16 + cl;
                b[nf] = *(const h8*)&Bs[r * 64 + ((c ^ (r & 7)) * 8)];
            }
#pragma unroll
            for (int mf = 0; mf < 2; ++mf)
#pragma unroll
                for (int nf = 0; nf < 2; ++nf)
                    acc[mf][nf] = MFMAH(a[mf], b[nf], acc[mf][nf]);
        }
    }

#pragma unroll
    for (int mf = 0; mf < 2; ++mf)
#pragma unroll
        for (int nf = 0; nf < 2; ++nf) {
            const int n  = n0 + wn * 32 + nf * 16 + cl;
            const int mb = m0 + wm * 32 + mf * 16 + rg * 4;
            const float bv = bo[n];
#pragma unroll
            for (int j = 0; j < 4; ++j)
                out[(size_t)(mb + j) * D_DIM + n] = acc[mf][nf][j] + bv;
        }
}

// ---------------------------------------------------------------------------
// Causal flash attention, fp16 MFMA, in-block KV split, swapped operands,
// in-register P, diagonal-only masking, T13 defer-rescale, pkrtz P-packing.
// (r18-proven — unchanged.) Balanced work pairing; LDS 64 KB -> 2 blocks/CU.
// ---------------------------------------------------------------------------
__global__ __launch_bounds__(512, 4) void attn_fused(
    const ush* __restrict__ Qg, const ush* __restrict__ Kg,
    const ush* __restrict__ Vtg, ush* __restrict__ Yf)
{
    extern __shared__ char smem[];
    const int b   = blockIdx.x;
    const int h   = b & 15;
    const int qt  = (b < 256) ? (31 - (b >> 4)) : ((b >> 4) - 16);
    const int q0  = qt * 64;
    const int tid = threadIdx.x;
    const int l   = tid & 63;
    const int wid = tid >> 6;
    const int grp = wid >> 2;            // 0 or 1
    const int w   = wid & 3;             // wave: q rows [w*16, w*16+16)
    const int cl  = l & 15;
    const int rg  = l >> 4;
    const int clx = cl & 7;
    const int tg  = tid & 255;

    char* gbase = smem + grp * 32768;
    ush* Ks = (ush*)gbase;               // [64][128] swz, 16 KB
    ush* Vs = (ush*)(gbase + 16384);     // [128][64] swz, 16 KB

    const int split = (qt + 2) >> 1;
    const int iters = split;
    const int t0    = grp ? split : 0;
    const int tcnt  = grp ? (qt + 1 - split) : split;

    const int qrow = q0 + w * 16 + cl;

    h8 qf[4];
#pragma unroll
    for (int kf = 0; kf < 4; ++kf)
        qf[kf] = *(const h8*)&Qg[(size_t)qrow * D_DIM + h * DHEAD + kf * 32 + rg * 8];

    v4f acc[8];
#pragma unroll
    for (int nf = 0; nf < 8; ++nf) acc[nf] = (v4f)0.f;
    float mrow = -INFINITY;
    float lsum = 0.f;

    auto stage = [&](int tile) {
#pragma unroll
        for (int i = 0; i < 4; ++i) {
            const int id = i * 256 + tg;
            const int kr = id >> 4, kc = id & 15;
            gload_lds16(&Kg[(size_t)(tile * 64 + kr) * D_DIM + h * DHEAD +
                            ((kc ^ (kr & 7)) * 8)], &Ks[id * 8]);
        }
#pragma unroll
        for (int i = 0; i < 4; ++i) {
            const int id = i * 256 + tg;
            const int vr = id >> 3, vc = id & 7;
            gload_lds16(&Vtg[(size_t)(h * DHEAD + vr) * D_DIM + tile * 64 +
                             ((vc ^ (vr & 7)) * 8)], &Vs[id * 8]);
        }
    };

    for (int t = 0; t < iters; ++t) {
        __syncthreads();                 // prev tile's Ks/Vs reads done
        if (t < tcnt) stage(t0 + t);
        __syncthreads();                 // staged data valid
        if (t < tcnt) {
            const int tile = t0 + t;

            // QK^T swapped: st[n][jj] = S[q=cl][kv = n*16 + rg*4 + jj]
            v4f st[4];
#pragma unroll
            for (int n = 0; n < 4; ++n) st[n] = (v4f)0.f;
            __builtin_amdgcn_s_setprio(1);
#pragma unroll
            for (int kf = 0; kf < 4; ++kf) {
#pragma unroll
                for (int n = 0; n < 4; ++n) {
                    const h8 kfr = *(const h8*)&Ks[(n * 16 + cl) * 128 +
                                    (((kf * 4 + rg) ^ clx) * 8)];
                    st[n] = MFMAH(kfr, qf[kf], st[n]);
                }
            }
            __builtin_amdgcn_s_setprio(0);

            float sv[4][4];
#pragma unroll
            for (int n = 0; n < 4; ++n)
#pragma unroll
                for (int jj = 0; jj < 4; ++jj) sv[n][jj] = st[n][jj];
            if (tile == qt) {            // diagonal tile only (uniform branch)
#pragma unroll
                for (int n = 0; n < 4; ++n)
#pragma unroll
                    for (int jj = 0; jj < 4; ++jj)
                        if (tile * 64 + n * 16 + rg * 4 + jj > qrow)
                            sv[n][jj] = -INFINITY;
            }
            float mx = sv[0][0];
#pragma unroll
            for (int n = 0; n < 4; ++n)
#pragma unroll
                for (int jj = 0; jj < 4; ++jj) mx = fmaxf(mx, sv[n][jj]);
            mx = fmaxf(mx, __shfl_xor(mx, 16));
            mx = fmaxf(mx, __shfl_xor(mx, 32));

            // T13 defer-rescale: skip corr + acc rescale when max didn't grow
            const bool noup = __all(mx <= mrow);
            const float mnew = noup ? mrow : fmaxf(mrow, mx);

            uint2 pk[4];
            float rs = 0.f;
#pragma unroll
            for (int n = 0; n < 4; ++n) {
                float p0 = exp2f(sv[n][0] - mnew);
                float p1 = exp2f(sv[n][1] - mnew);
                float p2 = exp2f(sv[n][2] - mnew);
                float p3 = exp2f(sv[n][3] - mnew);
                rs += (p0 + p1) + (p2 + p3);
                pk[n].x = pkrtz(p0, p1);
                pk[n].y = pkrtz(p2, p3);
            }
            rs += __shfl_xor(rs, 16);
            rs += __shfl_xor(rs, 32);

            if (noup) {
                lsum += rs;
            } else {
                const float corr = exp2f(mrow - mnew);
                lsum = lsum * corr + rs;
                mrow = mnew;
#pragma unroll
                for (int nf = 0; nf < 8; ++nf) acc[nf] *= corr;
            }

            // In-register P redistribution (intra-wave):
            const int s0 = cl + ((rg & 1) << 5);
            const int s1 = s0 + 16;
            const bool lo = (rg < 2);
            h8 pa[2];
#pragma unroll
            for (int kk = 0; kk < 2; ++kk) {
                union { uint4 u; h8 hv; } cv;
                const int xa = __shfl((int)pk[kk * 2].x, s0);
                const int xb = __shfl((int)pk[kk * 2 + 1].x, s0);
                const int ya = __shfl((int)pk[kk * 2].y, s0);
                const int yb = __shfl((int)pk[kk * 2 + 1].y, s0);
                const int za = __shfl((int)pk[kk * 2].x, s1);
                const int zb = __shfl((int)pk[kk * 2 + 1].x, s1);
                const int wa = __shfl((int)pk[kk * 2].y, s1);
                const int wb = __shfl((int)pk[kk * 2 + 1].y, s1);
                cv.u.x = (unsigned)(lo ? xa : xb);
                cv.u.y = (unsigned)(lo ? ya : yb);
                cv.u.z = (unsigned)(lo ? za : zb);
                cv.u.w = (unsigned)(lo ? wa : wb);
                pa[kk] = cv.hv;
            }

            // PV swapped: acc[nf] = MFMA(Vt_frag, P_frag)
            __builtin_amdgcn_s_setprio(1);
#pragma unroll
            for (int nf = 0; nf < 8; ++nf) {
#pragma unroll
                for (int kk = 0; kk < 2; ++kk) {
                    const h8 vb = *(const h8*)&Vs[(nf * 16 + cl) * 64 +
                                   (((kk * 4 + rg) ^ clx) * 8)];
                    acc[nf] = MFMAH(vb, pa[kk], acc[nf]);
                }
            }
            __builtin_amdgcn_s_setprio(0);
        }
    }

    // ---- in-LDS merge of the two KV-half partials (lane-local in q) ----
    float* mAcc = (float*)smem;              // [64][132] fp32, 33792 B
    float* mML  = (float*)(smem + 33792);    // [64][2]

    const int lr = w * 16 + cl;
    __syncthreads();                         // all compute done
    if (grp == 1) {
#pragma unroll
        for (int nf = 0; nf < 8; ++nf)
            *(v4f*)&mAcc[lr * 132 + nf * 16 + rg * 4] = acc[nf];
        if (rg == 0) {
            mML[lr * 2]     = mrow;
            mML[lr * 2 + 1] = lsum;
        }
    }
    __syncthreads();
    if (grp == 0) {
        const float m1 = mML[lr * 2];
        const float l1 = mML[lr * 2 + 1];
        const float ms = fmaxf(mrow, m1);
        const float e0 = exp2f(mrow - ms);
        const float e1 = exp2f(m1 - ms);
        const float inv = 1.0f / (lsum * e0 + l1 * e1);
        const float s0 = e0 * inv, s1 = e1 * inv;
#pragma unroll
        for (int nf = 0; nf < 8; ++nf) {
            const v4f a1 = *(const v4f*)&mAcc[lr * 132 + nf * 16 + rg * 4];
            ushort4 ph;
            ph.x = f2h(acc[nf][0] * s0 + a1[0] * s1);
            ph.y = f2h(acc[nf][1] * s0 + a1[1] * s1);
            ph.z = f2h(acc[nf][2] * s0 + a1[2] * s1);
            ph.w = f2h(acc[nf][3] * s0 + a1[3] * s1);
            const size_t o = (size_t)(q0 + lr) * D_DIM + h * DHEAD + nf * 16 + rg * 4;
            *(ushort4*)&Yf[o] = ph;
        }
    }
}

// ---------------------------------------------------------------------------
extern "C" void kernel_launch(void* const* d_in, const int* in_sizes, int n_in,
                              void* d_out, int out_size, void* d_ws, size_t ws_size,
                              hipStream_t stream)
{
    const float* x  = (const float*)d_in[0];
    const float* Wq = (const float*)d_in[1];
    const float* bq = (const float*)d_in[2];
    const float* Wk = (const float*)d_in[3];
    const float* bk = (const float*)d_in[4];
    const float* Wv = (const float*)d_in[5];
    const float* bv = (const float*)d_in[6];
    const float* Wo = (const float*)d_in[7];
    const float* bo = (const float*)d_in[8];
    float* out = (float*)d_out;

    const size_t mat = (size_t)T_DIM * D_DIM;
    // 1/sqrt(128) * log2(e): attention runs in exp2 domain
    const float qscale = 0.08838834764831845f * 1.4426950408889634f;

    const int attn_lds = 65536;
    hipFuncSetAttribute((const void*)attn_fused,
                        hipFuncAttributeMaxDynamicSharedMemorySize, attn_lds);

    // workspace: 8 fp16 matrices = 67.1 MB
    ush* xf   = (ush*)d_ws;        // becomes Yf after QKV (x dead then)
    ush* Qf   = xf  + mat;
    ush* Kf   = Qf  + mat;
    ush* Vtf  = Kf  + mat;
    ush* Wqf  = Vtf + mat;
    ush* Wkf  = Wqf + mat;
    ush* Wvf  = Wkf + mat;
    ush* Wof  = Wvf + mat;
    ush* Yf   = xf;

    Cvt5Args ca;
    ca.s[0] = x;  ca.d[0] = xf;
    ca.s[1] = Wq; ca.d[1] = Wqf;
    ca.s[2] = Wk; ca.d[2] = Wkf;
    ca.s[3] = Wv; ca.d[3] = Wvf;
    ca.s[4] = Wo; ca.d[4] = Wof;
    cvt5<<<dim3(mat / 2048, 5), 256, 0, stream>>>(ca);

    gemm_qkv_f16<<<1024, 256, 0, stream>>>(
        xf, Wqf, Wkf, Wvf, bq, bk, bv, qscale, Qf, Kf, Vtf);

    attn_fused<<<512, 512, attn_lds, stream>>>(Qf, Kf, Vtf, Yf);

    gemm_o_f16<<<1024, 256, 0, stream>>>(Yf, Wof, bo, out);
}

// Round 20
// 145.960 us; speedup vs baseline: 1.0539x; 1.0539x over previous
//
#include <hip/hip_runtime.h>
#include <hip/hip_fp16.h>
#include <math.h>

#define T_DIM 2048
#define D_DIM 2048
#define NHEAD 16
#define DHEAD 128

typedef _Float16 h8 __attribute__((ext_vector_type(8)));   // 8 fp16 (4 VGPRs)
typedef float v4f __attribute__((ext_vector_type(4)));
typedef unsigned short ush;

#define MFMAH(a, b, c) __builtin_amdgcn_mfma_f32_16x16x32_f16((a), (b), (c), 0, 0, 0)

__device__ __forceinline__ ush f2h(float f) {
    return __half_as_ushort(__float2half(f));   // RTN
}
__device__ __forceinline__ unsigned pack2(ush a, ush b) {
    return (unsigned)a | ((unsigned)b << 16);
}
__device__ __forceinline__ unsigned pkrtz(float a, float b) {   // v_cvt_pkrtz_f16_f32
    auto r = __builtin_amdgcn_cvt_pkrtz(a, b);  // __fp16 ext_vector_type(2)
    return __builtin_bit_cast(unsigned, r);
}

__device__ __forceinline__ void gload_lds16(const ush* g, ush* l) {
    __builtin_amdgcn_global_load_lds(
        (const __attribute__((address_space(1))) void*)g,
        (__attribute__((address_space(3))) void*)l, 16, 0, 0);
}

// 2-D region XCD swizzle for a 16(m) x 32(n) grid of 512 blocks (proven r9:
// FETCH 232->82MB). Each XCD owns an 8m x 8n region.
__device__ __forceinline__ void region_swizzle(int bid, int& m0, int& n0) {
    const int xcd = bid & 7;
    const int lg  = bid >> 3;
    const int mp  = ((xcd >> 2) << 3) + (lg >> 3);
    const int np  = ((xcd & 3) << 3) + (lg & 7);
    m0 = mp * 128;
    n0 = np * 64;
}

// ---------------------------------------------------------------------------
// Fused 5-matrix fp32 -> fp16 cast (x, Wq, Wk, Wv, Wo).
// ---------------------------------------------------------------------------
struct Cvt5Args { const float* s[5]; ush* d[5]; };

__global__ __launch_bounds__(256) void cvt5(Cvt5Args a)
{
    const int m = blockIdx.y;
    const float* X = a.s[m];
    ush* Dst = a.d[m];
    const int i = (blockIdx.x * 256 + threadIdx.x) * 8;
    const float4 p = *(const float4*)&X[i];
    const float4 q = *(const float4*)&X[i + 4];
    uint4 o;
    o.x = pack2(f2h(p.x), f2h(p.y));
    o.y = pack2(f2h(p.z), f2h(p.w));
    o.z = pack2(f2h(q.x), f2h(q.y));
    o.w = pack2(f2h(q.z), f2h(q.w));
    *(uint4*)&Dst[i] = o;
}

// ---------------------------------------------------------------------------
// FUSED QKV GEMM, plain fp16. 128x64 tile, BK=64, 256 threads = 4 waves
// (2m x 2n), wave-tile 64x32 (2.4 MFMA per ds_read_b128 — best measured
// ratio; r19's 64x64 reshape cut it to 1.5 and regressed). LDS 40 KB.
// Conflict-free XOR row geometry; region swizzle. (r18-proven)
// ---------------------------------------------------------------------------
__global__ __launch_bounds__(256, 2) void gemm_qkv_f16(
    const ush* __restrict__ xf,
    const ush* __restrict__ Wqf, const ush* __restrict__ Wkf,
    const ush* __restrict__ Wvf,
    const float* __restrict__ bq, const float* __restrict__ bk,
    const float* __restrict__ bv, float qscale,
    ush* __restrict__ Qo, ush* __restrict__ Ko, ush* __restrict__ Vto)
{
    __shared__ ush As[128 * 64];
    __shared__ ush Bs[3][64 * 64];

    const int tid = threadIdx.x;
    const int l   = tid & 63;
    const int wid = tid >> 6;      // 0..3
    const int wm  = wid >> 1;      // 0..1 (m half)
    const int wn  = wid & 1;       // 0..1 (n half)
    const int cl  = l & 15;
    const int rg  = l >> 4;

    int m0, n0;
    region_swizzle(blockIdx.x, m0, n0);

    const ush* Wf[3] = {Wqf, Wkf, Wvf};

    v4f acc[3][4][2];
#pragma unroll
    for (int wg = 0; wg < 3; ++wg)
#pragma unroll
        for (int mf = 0; mf < 4; ++mf)
#pragma unroll
            for (int nf = 0; nf < 2; ++nf) acc[wg][mf][nf] = (v4f)0.f;

    for (int ks = 0; ks < D_DIM / 64; ++ks) {
        const int k0 = ks * 64;
        __syncthreads();
#pragma unroll
        for (int i = 0; i < 4; ++i) {
            const int p   = i * 256 + tid;
            const int row = p >> 3;
            const int lc  = (p & 7) ^ (row & 7);
            gload_lds16(&xf[(size_t)(m0 + row) * D_DIM + k0 + lc * 8], &As[p * 8]);
        }
#pragma unroll
        for (int i = 0; i < 2; ++i) {
            const int p   = i * 256 + tid;
            const int row = p >> 3;
            const int lc  = (p & 7) ^ (row & 7);
            const size_t off = (size_t)(n0 + row) * D_DIM + k0 + lc * 8;
#pragma unroll
            for (int wg = 0; wg < 3; ++wg)
                gload_lds16(&Wf[wg][off], &Bs[wg][p * 8]);
        }
        __syncthreads();

#pragma unroll
        for (int kf = 0; kf < 2; ++kf) {
            const int c = kf * 4 + rg;
            h8 a[4];
#pragma unroll
            for (int mf = 0; mf < 4; ++mf) {
                const int r = wm * 64 + mf * 16 + cl;
                a[mf] = *(const h8*)&As[r * 64 + ((c ^ (r & 7)) * 8)];
            }
#pragma unroll
            for (int wg = 0; wg < 3; ++wg) {
                h8 b[2];
#pragma unroll
                for (int nf = 0; nf < 2; ++nf) {
                    const int r = wn * 32 + nf * 16 + cl;
                    b[nf] = *(const h8*)&Bs[wg][r * 64 + ((c ^ (r & 7)) * 8)];
                }
#pragma unroll
                for (int mf = 0; mf < 4; ++mf)
#pragma unroll
                    for (int nf = 0; nf < 2; ++nf)
                        acc[wg][mf][nf] = MFMAH(a[mf], b[nf], acc[wg][mf][nf]);
            }
        }
    }

#pragma unroll
    for (int mf = 0; mf < 4; ++mf)
#pragma unroll
        for (int nf = 0; nf < 2; ++nf) {
            const int n  = n0 + wn * 32 + nf * 16 + cl;
            const int mb = m0 + wm * 64 + mf * 16 + rg * 4;
            const float bvq = bq[n], bvk = bk[n], bvv = bv[n];
#pragma unroll
            for (int j = 0; j < 4; ++j) {
                Qo[(size_t)(mb + j) * D_DIM + n] =
                    f2h((acc[0][mf][nf][j] + bvq) * qscale);
                Ko[(size_t)(mb + j) * D_DIM + n] =
                    f2h(acc[1][mf][nf][j] + bvk);
            }
            ushort4 pk;
            pk.x = f2h(acc[2][mf][nf][0] + bvv);
            pk.y = f2h(acc[2][mf][nf][1] + bvv);
            pk.z = f2h(acc[2][mf][nf][2] + bvv);
            pk.w = f2h(acc[2][mf][nf][3] + bvv);
            *(ushort4*)&Vto[(size_t)n * D_DIM + mb] = pk;   // Vt[n][m..m+3]
        }
}

// ---------------------------------------------------------------------------
// O-projection GEMM, plain fp16. (r18-proven — unchanged)
// ---------------------------------------------------------------------------
__global__ __launch_bounds__(256, 2) void gemm_o_f16(
    const ush* __restrict__ Yf, const ush* __restrict__ Wof,
    const float* __restrict__ bo, float* __restrict__ out)
{
    __shared__ ush As[128 * 64];
    __shared__ ush Bs[64 * 64];

    const int tid = threadIdx.x;
    const int l   = tid & 63;
    const int wid = tid >> 6;
    const int wm  = wid >> 1;
    const int wn  = wid & 1;
    const int cl  = l & 15;
    const int rg  = l >> 4;

    int m0, n0;
    region_swizzle(blockIdx.x, m0, n0);

    v4f acc[4][2];
#pragma unroll
    for (int mf = 0; mf < 4; ++mf)
#pragma unroll
        for (int nf = 0; nf < 2; ++nf) acc[mf][nf] = (v4f)0.f;

    for (int ks = 0; ks < D_DIM / 64; ++ks) {
        const int k0 = ks * 64;
        __syncthreads();
#pragma unroll
        for (int i = 0; i < 4; ++i) {
            const int p   = i * 256 + tid;
            const int row = p >> 3;
            const int lc  = (p & 7) ^ (row & 7);
            gload_lds16(&Yf[(size_t)(m0 + row) * D_DIM + k0 + lc * 8], &As[p * 8]);
        }
#pragma unroll
        for (int i = 0; i < 2; ++i) {
            const int p   = i * 256 + tid;
            const int row = p >> 3;
            const int lc  = (p & 7) ^ (row & 7);
            gload_lds16(&Wof[(size_t)(n0 + row) * D_DIM + k0 + lc * 8], &Bs[p * 8]);
        }
        __syncthreads();

#pragma unroll
        for (int kf = 0; kf < 2; ++kf) {
            const int c = kf * 4 + rg;
            h8 a[4], b[2];
#pragma unroll
            for (int mf = 0; mf < 4; ++mf) {
                const int r = wm * 64 + mf * 16 + cl;
                a[mf] = *(const h8*)&As[r * 64 + ((c ^ (r & 7)) * 8)];
            }
#pragma unroll
            for (int nf = 0; nf < 2; ++nf) {
                const int r = wn * 32 + nf * 16 + cl;
                b[nf] = *(const h8*)&Bs[r * 64 + ((c ^ (r & 7)) * 8)];
            }
#pragma unroll
            for (int mf = 0; mf < 4; ++mf)
#pragma unroll
                for (int nf = 0; nf < 2; ++nf)
                    acc[mf][nf] = MFMAH(a[mf], b[nf], acc[mf][nf]);
        }
    }

#pragma unroll
    for (int mf = 0; mf < 4; ++mf)
#pragma unroll
        for (int nf = 0; nf < 2; ++nf) {
            const int n  = n0 + wn * 32 + nf * 16 + cl;
            const int mb = m0 + wm * 64 + mf * 16 + rg * 4;
            const float bv = bo[n];
#pragma unroll
            for (int j = 0; j < 4; ++j)
                out[(size_t)(mb + j) * D_DIM + n] = acc[mf][nf][j] + bv;
        }
}

// ---------------------------------------------------------------------------
// Causal flash attention, fp16 MFMA, in-block KV split, swapped operands,
// in-register P, diagonal-only masking, T13 defer-rescale, pkrtz P-packing.
// (r18-proven — unchanged.) Balanced work pairing; LDS 64 KB -> 2 blocks/CU.
// ---------------------------------------------------------------------------
__global__ __launch_bounds__(512, 4) void attn_fused(
    const ush* __restrict__ Qg, const ush* __restrict__ Kg,
    const ush* __restrict__ Vtg, ush* __restrict__ Yf)
{
    extern __shared__ char smem[];
    const int b   = blockIdx.x;
    const int h   = b & 15;
    const int qt  = (b < 256) ? (31 - (b >> 4)) : ((b >> 4) - 16);
    const int q0  = qt * 64;
    const int tid = threadIdx.x;
    const int l   = tid & 63;
    const int wid = tid >> 6;
    const int grp = wid >> 2;            // 0 or 1
    const int w   = wid & 3;             // wave: q rows [w*16, w*16+16)
    const int cl  = l & 15;
    const int rg  = l >> 4;
    const int clx = cl & 7;
    const int tg  = tid & 255;

    char* gbase = smem + grp * 32768;
    ush* Ks = (ush*)gbase;               // [64][128] swz, 16 KB
    ush* Vs = (ush*)(gbase + 16384);     // [128][64] swz, 16 KB

    const int split = (qt + 2) >> 1;
    const int iters = split;
    const int t0    = grp ? split : 0;
    const int tcnt  = grp ? (qt + 1 - split) : split;

    const int qrow = q0 + w * 16 + cl;

    h8 qf[4];
#pragma unroll
    for (int kf = 0; kf < 4; ++kf)
        qf[kf] = *(const h8*)&Qg[(size_t)qrow * D_DIM + h * DHEAD + kf * 32 + rg * 8];

    v4f acc[8];
#pragma unroll
    for (int nf = 0; nf < 8; ++nf) acc[nf] = (v4f)0.f;
    float mrow = -INFINITY;
    float lsum = 0.f;

    auto stage = [&](int tile) {
#pragma unroll
        for (int i = 0; i < 4; ++i) {
            const int id = i * 256 + tg;
            const int kr = id >> 4, kc = id & 15;
            gload_lds16(&Kg[(size_t)(tile * 64 + kr) * D_DIM + h * DHEAD +
                            ((kc ^ (kr & 7)) * 8)], &Ks[id * 8]);
        }
#pragma unroll
        for (int i = 0; i < 4; ++i) {
            const int id = i * 256 + tg;
            const int vr = id >> 3, vc = id & 7;
            gload_lds16(&Vtg[(size_t)(h * DHEAD + vr) * D_DIM + tile * 64 +
                             ((vc ^ (vr & 7)) * 8)], &Vs[id * 8]);
        }
    };

    for (int t = 0; t < iters; ++t) {
        __syncthreads();                 // prev tile's Ks/Vs reads done
        if (t < tcnt) stage(t0 + t);
        __syncthreads();                 // staged data valid
        if (t < tcnt) {
            const int tile = t0 + t;

            // QK^T swapped: st[n][jj] = S[q=cl][kv = n*16 + rg*4 + jj]
            v4f st[4];
#pragma unroll
            for (int n = 0; n < 4; ++n) st[n] = (v4f)0.f;
            __builtin_amdgcn_s_setprio(1);
#pragma unroll
            for (int kf = 0; kf < 4; ++kf) {
#pragma unroll
                for (int n = 0; n < 4; ++n) {
                    const h8 kfr = *(const h8*)&Ks[(n * 16 + cl) * 128 +
                                    (((kf * 4 + rg) ^ clx) * 8)];
                    st[n] = MFMAH(kfr, qf[kf], st[n]);
                }
            }
            __builtin_amdgcn_s_setprio(0);

            float sv[4][4];
#pragma unroll
            for (int n = 0; n < 4; ++n)
#pragma unroll
                for (int jj = 0; jj < 4; ++jj) sv[n][jj] = st[n][jj];
            if (tile == qt) {            // diagonal tile only (uniform branch)
#pragma unroll
                for (int n = 0; n < 4; ++n)
#pragma unroll
                    for (int jj = 0; jj < 4; ++jj)
                        if (tile * 64 + n * 16 + rg * 4 + jj > qrow)
                            sv[n][jj] = -INFINITY;
            }
            float mx = sv[0][0];
#pragma unroll
            for (int n = 0; n < 4; ++n)
#pragma unroll
                for (int jj = 0; jj < 4; ++jj) mx = fmaxf(mx, sv[n][jj]);
            mx = fmaxf(mx, __shfl_xor(mx, 16));
            mx = fmaxf(mx, __shfl_xor(mx, 32));

            // T13 defer-rescale: skip corr + acc rescale when max didn't grow
            const bool noup = __all(mx <= mrow);
            const float mnew = noup ? mrow : fmaxf(mrow, mx);

            uint2 pk[4];
            float rs = 0.f;
#pragma unroll
            for (int n = 0; n < 4; ++n) {
                float p0 = exp2f(sv[n][0] - mnew);
                float p1 = exp2f(sv[n][1] - mnew);
                float p2 = exp2f(sv[n][2] - mnew);
                float p3 = exp2f(sv[n][3] - mnew);
                rs += (p0 + p1) + (p2 + p3);
                pk[n].x = pkrtz(p0, p1);
                pk[n].y = pkrtz(p2, p3);
            }
            rs += __shfl_xor(rs, 16);
            rs += __shfl_xor(rs, 32);

            if (noup) {
                lsum += rs;
            } else {
                const float corr = exp2f(mrow - mnew);
                lsum = lsum * corr + rs;
                mrow = mnew;
#pragma unroll
                for (int nf = 0; nf < 8; ++nf) acc[nf] *= corr;
            }

            // In-register P redistribution (intra-wave):
            const int s0 = cl + ((rg & 1) << 5);
            const int s1 = s0 + 16;
            const bool lo = (rg < 2);
            h8 pa[2];
#pragma unroll
            for (int kk = 0; kk < 2; ++kk) {
                union { uint4 u; h8 hv; } cv;
                const int xa = __shfl((int)pk[kk * 2].x, s0);
                const int xb = __shfl((int)pk[kk * 2 + 1].x, s0);
                const int ya = __shfl((int)pk[kk * 2].y, s0);
                const int yb = __shfl((int)pk[kk * 2 + 1].y, s0);
                const int za = __shfl((int)pk[kk * 2].x, s1);
                const int zb = __shfl((int)pk[kk * 2 + 1].x, s1);
                const int wa = __shfl((int)pk[kk * 2].y, s1);
                const int wb = __shfl((int)pk[kk * 2 + 1].y, s1);
                cv.u.x = (unsigned)(lo ? xa : xb);
                cv.u.y = (unsigned)(lo ? ya : yb);
                cv.u.z = (unsigned)(lo ? za : zb);
                cv.u.w = (unsigned)(lo ? wa : wb);
                pa[kk] = cv.hv;
            }

            // PV swapped: acc[nf] = MFMA(Vt_frag, P_frag)
            __builtin_amdgcn_s_setprio(1);
#pragma unroll
            for (int nf = 0; nf < 8; ++nf) {
#pragma unroll
                for (int kk = 0; kk < 2; ++kk) {
                    const h8 vb = *(const h8*)&Vs[(nf * 16 + cl) * 64 +
                                   (((kk * 4 + rg) ^ clx) * 8)];
                    acc[nf] = MFMAH(vb, pa[kk], acc[nf]);
                }
            }
            __builtin_amdgcn_s_setprio(0);
        }
    }

    // ---- in-LDS merge of the two KV-half partials (lane-local in q) ----
    float* mAcc = (float*)smem;              // [64][132] fp32, 33792 B
    float* mML  = (float*)(smem + 33792);    // [64][2]

    const int lr = w * 16 + cl;
    __syncthreads();                         // all compute done
    if (grp == 1) {
#pragma unroll
        for (int nf = 0; nf < 8; ++nf)
            *(v4f*)&mAcc[lr * 132 + nf * 16 + rg * 4] = acc[nf];
        if (rg == 0) {
            mML[lr * 2]     = mrow;
            mML[lr * 2 + 1] = lsum;
        }
    }
    __syncthreads();
    if (grp == 0) {
        const float m1 = mML[lr * 2];
        const float l1 = mML[lr * 2 + 1];
        const float ms = fmaxf(mrow, m1);
        const float e0 = exp2f(mrow - ms);
        const float e1 = exp2f(m1 - ms);
        const float inv = 1.0f / (lsum * e0 + l1 * e1);
        const float s0 = e0 * inv, s1 = e1 * inv;
#pragma unroll
        for (int nf = 0; nf < 8; ++nf) {
            const v4f a1 = *(const v4f*)&mAcc[lr * 132 + nf * 16 + rg * 4];
            ushort4 ph;
            ph.x = f2h(acc[nf][0] * s0 + a1[0] * s1);
            ph.y = f2h(acc[nf][1] * s0 + a1[1] * s1);
            ph.z = f2h(acc[nf][2] * s0 + a1[2] * s1);
            ph.w = f2h(acc[nf][3] * s0 + a1[3] * s1);
            const size_t o = (size_t)(q0 + lr) * D_DIM + h * DHEAD + nf * 16 + rg * 4;
            *(ushort4*)&Yf[o] = ph;
        }
    }
}

// ---------------------------------------------------------------------------
extern "C" void kernel_launch(void* const* d_in, const int* in_sizes, int n_in,
                              void* d_out, int out_size, void* d_ws, size_t ws_size,
                              hipStream_t stream)
{
    const float* x  = (const float*)d_in[0];
    const float* Wq = (const float*)d_in[1];
    const float* bq = (const float*)d_in[2];
    const float* Wk = (const float*)d_in[3];
    const float* bk = (const float*)d_in[4];
    const float* Wv = (const float*)d_in[5];
    const float* bv = (const float*)d_in[6];
    const float* Wo = (const float*)d_in[7];
    const float* bo = (const float*)d_in[8];
    float* out = (float*)d_out;

    const size_t mat = (size_t)T_DIM * D_DIM;
    // 1/sqrt(128) * log2(e): attention runs in exp2 domain
    const float qscale = 0.08838834764831845f * 1.4426950408889634f;

    const int attn_lds = 65536;
    hipFuncSetAttribute((const void*)attn_fused,
                        hipFuncAttributeMaxDynamicSharedMemorySize, attn_lds);

    // workspace: 8 fp16 matrices = 67.1 MB
    ush* xf   = (ush*)d_ws;        // becomes Yf after QKV (x dead then)
    ush* Qf   = xf  + mat;
    ush* Kf   = Qf  + mat;
    ush* Vtf  = Kf  + mat;
    ush* Wqf  = Vtf + mat;
    ush* Wkf  = Wqf + mat;
    ush* Wvf  = Wkf + mat;
    ush* Wof  = Wvf + mat;
    ush* Yf   = xf;

    Cvt5Args ca;
    ca.s[0] = x;  ca.d[0] = xf;
    ca.s[1] = Wq; ca.d[1] = Wqf;
    ca.s[2] = Wk; ca.d[2] = Wkf;
    ca.s[3] = Wv; ca.d[3] = Wvf;
    ca.s[4] = Wo; ca.d[4] = Wof;
    cvt5<<<dim3(mat / 2048, 5), 256, 0, stream>>>(ca);

    gemm_qkv_f16<<<512, 256, 0, stream>>>(
        xf, Wqf, Wkf, Wvf, bq, bk, bv, qscale, Qf, Kf, Vtf);

    attn_fused<<<512, 512, attn_lds, stream>>>(Qf, Kf, Vtf, Yf);

    gemm_o_f16<<<512, 256, 0, stream>>>(Yf, Wof, bo, out);
}

// Round 21
// 145.550 us; speedup vs baseline: 1.0569x; 1.0028x over previous
//
#include <hip/hip_runtime.h>
#include <hip/hip_fp16.h>
#include <math.h>

#define T_DIM 2048
#define D_DIM 2048
#define NHEAD 16
#define DHEAD 128

typedef _Float16 h8 __attribute__((ext_vector_type(8)));   // 8 fp16 (4 VGPRs)
typedef float v4f __attribute__((ext_vector_type(4)));
typedef unsigned short ush;

#define MFMAH(a, b, c) __builtin_amdgcn_mfma_f32_16x16x32_f16((a), (b), (c), 0, 0, 0)

__device__ __forceinline__ ush f2h(float f) {
    return __half_as_ushort(__float2half(f));   // RTN
}
__device__ __forceinline__ unsigned pack2(ush a, ush b) {
    return (unsigned)a | ((unsigned)b << 16);
}
__device__ __forceinline__ unsigned pkrtz(float a, float b) {   // v_cvt_pkrtz_f16_f32
    auto r = __builtin_amdgcn_cvt_pkrtz(a, b);  // __fp16 ext_vector_type(2)
    return __builtin_bit_cast(unsigned, r);
}

__device__ __forceinline__ void gload_lds16(const ush* g, ush* l) {
    __builtin_amdgcn_global_load_lds(
        (const __attribute__((address_space(1))) void*)g,
        (__attribute__((address_space(3))) void*)l, 16, 0, 0);
}

// 2-D region XCD swizzle for a 16(m) x 32(n) grid of 512 blocks (proven r9:
// FETCH 232->82MB). Each XCD owns an 8m x 8n region.
__device__ __forceinline__ void region_swizzle(int bid, int& m0, int& n0) {
    const int xcd = bid & 7;
    const int lg  = bid >> 3;
    const int mp  = ((xcd >> 2) << 3) + (lg >> 3);
    const int np  = ((xcd & 3) << 3) + (lg & 7);
    m0 = mp * 128;
    n0 = np * 64;
}

// ---------------------------------------------------------------------------
// Fused 5-matrix fp32 -> fp16 cast (x, Wq, Wk, Wv, Wo).
// ---------------------------------------------------------------------------
struct Cvt5Args { const float* s[5]; ush* d[5]; };

__global__ __launch_bounds__(256) void cvt5(Cvt5Args a)
{
    const int m = blockIdx.y;
    const float* X = a.s[m];
    ush* Dst = a.d[m];
    const int i = (blockIdx.x * 256 + threadIdx.x) * 8;
    const float4 p = *(const float4*)&X[i];
    const float4 q = *(const float4*)&X[i + 4];
    uint4 o;
    o.x = pack2(f2h(p.x), f2h(p.y));
    o.y = pack2(f2h(p.z), f2h(p.w));
    o.z = pack2(f2h(q.x), f2h(q.y));
    o.w = pack2(f2h(q.z), f2h(q.w));
    *(uint4*)&Dst[i] = o;
}

// ---------------------------------------------------------------------------
// FUSED QKV GEMM, plain fp16. 128x64 tile, BK=64, 256 threads = 4 waves
// (2m x 2n), wave-tile 64x32 (2.4 MFMA per ds_read_b128 — best measured
// ratio). LDS 40 KB. Conflict-free XOR row geometry; region swizzle.
// ---------------------------------------------------------------------------
__global__ __launch_bounds__(256, 2) void gemm_qkv_f16(
    const ush* __restrict__ xf,
    const ush* __restrict__ Wqf, const ush* __restrict__ Wkf,
    const ush* __restrict__ Wvf,
    const float* __restrict__ bq, const float* __restrict__ bk,
    const float* __restrict__ bv, float qscale,
    ush* __restrict__ Qo, ush* __restrict__ Ko, ush* __restrict__ Vto)
{
    __shared__ ush As[128 * 64];
    __shared__ ush Bs[3][64 * 64];

    const int tid = threadIdx.x;
    const int l   = tid & 63;
    const int wid = tid >> 6;      // 0..3
    const int wm  = wid >> 1;      // 0..1 (m half)
    const int wn  = wid & 1;       // 0..1 (n half)
    const int cl  = l & 15;
    const int rg  = l >> 4;

    int m0, n0;
    region_swizzle(blockIdx.x, m0, n0);

    const ush* Wf[3] = {Wqf, Wkf, Wvf};

    v4f acc[3][4][2];
#pragma unroll
    for (int wg = 0; wg < 3; ++wg)
#pragma unroll
        for (int mf = 0; mf < 4; ++mf)
#pragma unroll
            for (int nf = 0; nf < 2; ++nf) acc[wg][mf][nf] = (v4f)0.f;

    for (int ks = 0; ks < D_DIM / 64; ++ks) {
        const int k0 = ks * 64;
        __syncthreads();
#pragma unroll
        for (int i = 0; i < 4; ++i) {
            const int p   = i * 256 + tid;
            const int row = p >> 3;
            const int lc  = (p & 7) ^ (row & 7);
            gload_lds16(&xf[(size_t)(m0 + row) * D_DIM + k0 + lc * 8], &As[p * 8]);
        }
#pragma unroll
        for (int i = 0; i < 2; ++i) {
            const int p   = i * 256 + tid;
            const int row = p >> 3;
            const int lc  = (p & 7) ^ (row & 7);
            const size_t off = (size_t)(n0 + row) * D_DIM + k0 + lc * 8;
#pragma unroll
            for (int wg = 0; wg < 3; ++wg)
                gload_lds16(&Wf[wg][off], &Bs[wg][p * 8]);
        }
        __syncthreads();

#pragma unroll
        for (int kf = 0; kf < 2; ++kf) {
            const int c = kf * 4 + rg;
            h8 a[4];
#pragma unroll
            for (int mf = 0; mf < 4; ++mf) {
                const int r = wm * 64 + mf * 16 + cl;
                a[mf] = *(const h8*)&As[r * 64 + ((c ^ (r & 7)) * 8)];
            }
#pragma unroll
            for (int wg = 0; wg < 3; ++wg) {
                h8 b[2];
#pragma unroll
                for (int nf = 0; nf < 2; ++nf) {
                    const int r = wn * 32 + nf * 16 + cl;
                    b[nf] = *(const h8*)&Bs[wg][r * 64 + ((c ^ (r & 7)) * 8)];
                }
#pragma unroll
                for (int mf = 0; mf < 4; ++mf)
#pragma unroll
                    for (int nf = 0; nf < 2; ++nf)
                        acc[wg][mf][nf] = MFMAH(a[mf], b[nf], acc[wg][mf][nf]);
            }
        }
    }

#pragma unroll
    for (int mf = 0; mf < 4; ++mf)
#pragma unroll
        for (int nf = 0; nf < 2; ++nf) {
            const int n  = n0 + wn * 32 + nf * 16 + cl;
            const int mb = m0 + wm * 64 + mf * 16 + rg * 4;
            const float bvq = bq[n], bvk = bk[n], bvv = bv[n];
#pragma unroll
            for (int j = 0; j < 4; ++j) {
                Qo[(size_t)(mb + j) * D_DIM + n] =
                    f2h((acc[0][mf][nf][j] + bvq) * qscale);
                Ko[(size_t)(mb + j) * D_DIM + n] =
                    f2h(acc[1][mf][nf][j] + bvk);
            }
            ushort4 pk;
            pk.x = f2h(acc[2][mf][nf][0] + bvv);
            pk.y = f2h(acc[2][mf][nf][1] + bvv);
            pk.z = f2h(acc[2][mf][nf][2] + bvv);
            pk.w = f2h(acc[2][mf][nf][3] + bvv);
            *(ushort4*)&Vto[(size_t)n * D_DIM + mb] = pk;   // Vt[n][m..m+3]
        }
}

// ---------------------------------------------------------------------------
// O-projection GEMM, plain fp16. (r18-proven — unchanged)
// ---------------------------------------------------------------------------
__global__ __launch_bounds__(256, 2) void gemm_o_f16(
    const ush* __restrict__ Yf, const ush* __restrict__ Wof,
    const float* __restrict__ bo, float* __restrict__ out)
{
    __shared__ ush As[128 * 64];
    __shared__ ush Bs[64 * 64];

    const int tid = threadIdx.x;
    const int l   = tid & 63;
    const int wid = tid >> 6;
    const int wm  = wid >> 1;
    const int wn  = wid & 1;
    const int cl  = l & 15;
    const int rg  = l >> 4;

    int m0, n0;
    region_swizzle(blockIdx.x, m0, n0);

    v4f acc[4][2];
#pragma unroll
    for (int mf = 0; mf < 4; ++mf)
#pragma unroll
        for (int nf = 0; nf < 2; ++nf) acc[mf][nf] = (v4f)0.f;

    for (int ks = 0; ks < D_DIM / 64; ++ks) {
        const int k0 = ks * 64;
        __syncthreads();
#pragma unroll
        for (int i = 0; i < 4; ++i) {
            const int p   = i * 256 + tid;
            const int row = p >> 3;
            const int lc  = (p & 7) ^ (row & 7);
            gload_lds16(&Yf[(size_t)(m0 + row) * D_DIM + k0 + lc * 8], &As[p * 8]);
        }
#pragma unroll
        for (int i = 0; i < 2; ++i) {
            const int p   = i * 256 + tid;
            const int row = p >> 3;
            const int lc  = (p & 7) ^ (row & 7);
            gload_lds16(&Wof[(size_t)(n0 + row) * D_DIM + k0 + lc * 8], &Bs[p * 8]);
        }
        __syncthreads();

#pragma unroll
        for (int kf = 0; kf < 2; ++kf) {
            const int c = kf * 4 + rg;
            h8 a[4], b[2];
#pragma unroll
            for (int mf = 0; mf < 4; ++mf) {
                const int r = wm * 64 + mf * 16 + cl;
                a[mf] = *(const h8*)&As[r * 64 + ((c ^ (r & 7)) * 8)];
            }
#pragma unroll
            for (int nf = 0; nf < 2; ++nf) {
                const int r = wn * 32 + nf * 16 + cl;
                b[nf] = *(const h8*)&Bs[r * 64 + ((c ^ (r & 7)) * 8)];
            }
#pragma unroll
            for (int mf = 0; mf < 4; ++mf)
#pragma unroll
                for (int nf = 0; nf < 2; ++nf)
                    acc[mf][nf] = MFMAH(a[mf], b[nf], acc[mf][nf]);
        }
    }

#pragma unroll
    for (int mf = 0; mf < 4; ++mf)
#pragma unroll
        for (int nf = 0; nf < 2; ++nf) {
            const int n  = n0 + wn * 32 + nf * 16 + cl;
            const int mb = m0 + wm * 64 + mf * 16 + rg * 4;
            const float bv = bo[n];
#pragma unroll
            for (int j = 0; j < 4; ++j)
                out[(size_t)(mb + j) * D_DIM + n] = acc[mf][nf][j] + bv;
        }
}

// ---------------------------------------------------------------------------
// Causal flash attention, fp16 MFMA, in-block KV split, swapped operands,
// in-register P, diagonal-only masking, T13 defer-rescale, pkrtz P-packing.
// Balanced work pairing; LDS 64 KB -> 2 blocks/CU. (r18-proven)
// ---------------------------------------------------------------------------
__global__ __launch_bounds__(512, 4) void attn_fused(
    const ush* __restrict__ Qg, const ush* __restrict__ Kg,
    const ush* __restrict__ Vtg, ush* __restrict__ Yf)
{
    extern __shared__ char smem[];
    const int b   = blockIdx.x;
    const int h   = b & 15;
    const int qt  = (b < 256) ? (31 - (b >> 4)) : ((b >> 4) - 16);
    const int q0  = qt * 64;
    const int tid = threadIdx.x;
    const int l   = tid & 63;
    const int wid = tid >> 6;
    const int grp = wid >> 2;            // 0 or 1
    const int w   = wid & 3;             // wave: q rows [w*16, w*16+16)
    const int cl  = l & 15;
    const int rg  = l >> 4;
    const int clx = cl & 7;
    const int tg  = tid & 255;

    char* gbase = smem + grp * 32768;
    ush* Ks = (ush*)gbase;               // [64][128] swz, 16 KB
    ush* Vs = (ush*)(gbase + 16384);     // [128][64] swz, 16 KB

    const int split = (qt + 2) >> 1;
    const int iters = split;
    const int t0    = grp ? split : 0;
    const int tcnt  = grp ? (qt + 1 - split) : split;

    const int qrow = q0 + w * 16 + cl;

    h8 qf[4];
#pragma unroll
    for (int kf = 0; kf < 4; ++kf)
        qf[kf] = *(const h8*)&Qg[(size_t)qrow * D_DIM + h * DHEAD + kf * 32 + rg * 8];

    v4f acc[8];
#pragma unroll
    for (int nf = 0; nf < 8; ++nf) acc[nf] = (v4f)0.f;
    float mrow = -INFINITY;
    float lsum = 0.f;

    auto stage = [&](int tile) {
#pragma unroll
        for (int i = 0; i < 4; ++i) {
            const int id = i * 256 + tg;
            const int kr = id >> 4, kc = id & 15;
            gload_lds16(&Kg[(size_t)(tile * 64 + kr) * D_DIM + h * DHEAD +
                            ((kc ^ (kr & 7)) * 8)], &Ks[id * 8]);
        }
#pragma unroll
        for (int i = 0; i < 4; ++i) {
            const int id = i * 256 + tg;
            const int vr = id >> 3, vc = id & 7;
            gload_lds16(&Vtg[(size_t)(h * DHEAD + vr) * D_DIM + tile * 64 +
                             ((vc ^ (vr & 7)) * 8)], &Vs[id * 8]);
        }
    };

    for (int t = 0; t < iters; ++t) {
        __syncthreads();                 // prev tile's Ks/Vs reads done
        if (t < tcnt) stage(t0 + t);
        __syncthreads();                 // staged data valid
        if (t < tcnt) {
            const int tile = t0 + t;

            // QK^T swapped: st[n][jj] = S[q=cl][kv = n*16 + rg*4 + jj]
            v4f st[4];
#pragma unroll
            for (int n = 0; n < 4; ++n) st[n] = (v4f)0.f;
            __builtin_amdgcn_s_setprio(1);
#pragma unroll
            for (int kf = 0; kf < 4; ++kf) {
#pragma unroll
                for (int n = 0; n < 4; ++n) {
                    const h8 kfr = *(const h8*)&Ks[(n * 16 + cl) * 128 +
                                    (((kf * 4 + rg) ^ clx) * 8)];
                    st[n] = MFMAH(kfr, qf[kf], st[n]);
                }
            }
            __builtin_amdgcn_s_setprio(0);

            float sv[4][4];
#pragma unroll
            for (int n = 0; n < 4; ++n)
#pragma unroll
                for (int jj = 0; jj < 4; ++jj) sv[n][jj] = st[n][jj];
            if (tile == qt) {            // diagonal tile only (uniform branch)
#pragma unroll
                for (int n = 0; n < 4; ++n)
#pragma unroll
                    for (int jj = 0; jj < 4; ++jj)
                        if (tile * 64 + n * 16 + rg * 4 + jj > qrow)
                            sv[n][jj] = -INFINITY;
            }
            float mx = sv[0][0];
#pragma unroll
            for (int n = 0; n < 4; ++n)
#pragma unroll
                for (int jj = 0; jj < 4; ++jj) mx = fmaxf(mx, sv[n][jj]);
            mx = fmaxf(mx, __shfl_xor(mx, 16));
            mx = fmaxf(mx, __shfl_xor(mx, 32));

            // T13 defer-rescale: skip corr + acc rescale when max didn't grow
            const bool noup = __all(mx <= mrow);
            const float mnew = noup ? mrow : fmaxf(mrow, mx);

            uint2 pk[4];
            float rs = 0.f;
#pragma unroll
            for (int n = 0; n < 4; ++n) {
                float p0 = exp2f(sv[n][0] - mnew);
                float p1 = exp2f(sv[n][1] - mnew);
                float p2 = exp2f(sv[n][2] - mnew);
                float p3 = exp2f(sv[n][3] - mnew);
                rs += (p0 + p1) + (p2 + p3);
                pk[n].x = pkrtz(p0, p1);
                pk[n].y = pkrtz(p2, p3);
            }
            rs += __shfl_xor(rs, 16);
            rs += __shfl_xor(rs, 32);

            if (noup) {
                lsum += rs;
            } else {
                const float corr = exp2f(mrow - mnew);
                lsum = lsum * corr + rs;
                mrow = mnew;
#pragma unroll
                for (int nf = 0; nf < 8; ++nf) acc[nf] *= corr;
            }

            // In-register P redistribution (intra-wave):
            const int s0 = cl + ((rg & 1) << 5);
            const int s1 = s0 + 16;
            const bool lo = (rg < 2);
            h8 pa[2];
#pragma unroll
            for (int kk = 0; kk < 2; ++kk) {
                union { uint4 u; h8 hv; } cv;
                const int xa = __shfl((int)pk[kk * 2].x, s0);
                const int xb = __shfl((int)pk[kk * 2 + 1].x, s0);
                const int ya = __shfl((int)pk[kk * 2].y, s0);
                const int yb = __shfl((int)pk[kk * 2 + 1].y, s0);
                const int za = __shfl((int)pk[kk * 2].x, s1);
                const int zb = __shfl((int)pk[kk * 2 + 1].x, s1);
                const int wa = __shfl((int)pk[kk * 2].y, s1);
                const int wb = __shfl((int)pk[kk * 2 + 1].y, s1);
                cv.u.x = (unsigned)(lo ? xa : xb);
                cv.u.y = (unsigned)(lo ? ya : yb);
                cv.u.z = (unsigned)(lo ? za : zb);
                cv.u.w = (unsigned)(lo ? wa : wb);
                pa[kk] = cv.hv;
            }

            // PV swapped: acc[nf] = MFMA(Vt_frag, P_frag)
            __builtin_amdgcn_s_setprio(1);
#pragma unroll
            for (int nf = 0; nf < 8; ++nf) {
#pragma unroll
                for (int kk = 0; kk < 2; ++kk) {
                    const h8 vb = *(const h8*)&Vs[(nf * 16 + cl) * 64 +
                                   (((kk * 4 + rg) ^ clx) * 8)];
                    acc[nf] = MFMAH(vb, pa[kk], acc[nf]);
                }
            }
            __builtin_amdgcn_s_setprio(0);
        }
    }

    // ---- in-LDS merge of the two KV-half partials (lane-local in q) ----
    float* mAcc = (float*)smem;              // [64][132] fp32, 33792 B
    float* mML  = (float*)(smem + 33792);    // [64][2]

    const int lr = w * 16 + cl;
    __syncthreads();                         // all compute done
    if (grp == 1) {
#pragma unroll
        for (int nf = 0; nf < 8; ++nf)
            *(v4f*)&mAcc[lr * 132 + nf * 16 + rg * 4] = acc[nf];
        if (rg == 0) {
            mML[lr * 2]     = mrow;
            mML[lr * 2 + 1] = lsum;
        }
    }
    __syncthreads();
    if (grp == 0) {
        const float m1 = mML[lr * 2];
        const float l1 = mML[lr * 2 + 1];
        const float ms = fmaxf(mrow, m1);
        const float e0 = exp2f(mrow - ms);
        const float e1 = exp2f(m1 - ms);
        const float inv = 1.0f / (lsum * e0 + l1 * e1);
        const float s0 = e0 * inv, s1 = e1 * inv;
#pragma unroll
        for (int nf = 0; nf < 8; ++nf) {
            const v4f a1 = *(const v4f*)&mAcc[lr * 132 + nf * 16 + rg * 4];
            ushort4 ph;
            ph.x = f2h(acc[nf][0] * s0 + a1[0] * s1);
            ph.y = f2h(acc[nf][1] * s0 + a1[1] * s1);
            ph.z = f2h(acc[nf][2] * s0 + a1[2] * s1);
            ph.w = f2h(acc[nf][3] * s0 + a1[3] * s1);
            const size_t o = (size_t)(q0 + lr) * D_DIM + h * DHEAD + nf * 16 + rg * 4;
            *(ushort4*)&Yf[o] = ph;
        }
    }
}

// ---------------------------------------------------------------------------
extern "C" void kernel_launch(void* const* d_in, const int* in_sizes, int n_in,
                              void* d_out, int out_size, void* d_ws, size_t ws_size,
                              hipStream_t stream)
{
    const float* x  = (const float*)d_in[0];
    const float* Wq = (const float*)d_in[1];
    const float* bq = (const float*)d_in[2];
    const float* Wk = (const float*)d_in[3];
    const float* bk = (const float*)d_in[4];
    const float* Wv = (const float*)d_in[5];
    const float* bv = (const float*)d_in[6];
    const float* Wo = (const float*)d_in[7];
    const float* bo = (const float*)d_in[8];
    float* out = (float*)d_out;

    const size_t mat = (size_t)T_DIM * D_DIM;
    // 1/sqrt(128) * log2(e): attention runs in exp2 domain
    const float qscale = 0.08838834764831845f * 1.4426950408889634f;

    const int attn_lds = 65536;
    hipFuncSetAttribute((const void*)attn_fused,
                        hipFuncAttributeMaxDynamicSharedMemorySize, attn_lds);

    // workspace: 8 fp16 matrices = 67.1 MB
    ush* xf   = (ush*)d_ws;        // becomes Yf after QKV (x dead then)
    ush* Qf   = xf  + mat;
    ush* Kf   = Qf  + mat;
    ush* Vtf  = Kf  + mat;
    ush* Wqf  = Vtf + mat;
    ush* Wkf  = Wqf + mat;
    ush* Wvf  = Wkf + mat;
    ush* Wof  = Wvf + mat;
    ush* Yf   = xf;

    Cvt5Args ca;
    ca.s[0] = x;  ca.d[0] = xf;
    ca.s[1] = Wq; ca.d[1] = Wqf;
    ca.s[2] = Wk; ca.d[2] = Wkf;
    ca.s[3] = Wv; ca.d[3] = Wvf;
    ca.s[4] = Wo; ca.d[4] = Wof;
    cvt5<<<dim3(mat / 2048, 5), 256, 0, stream>>>(ca);

    gemm_qkv_f16<<<512, 256, 0, stream>>>(
        xf, Wqf, Wkf, Wvf, bq, bk, bv, qscale, Qf, Kf, Vtf);

    attn_fused<<<512, 512, attn_lds, stream>>>(Qf, Kf, Vtf, Yf);

    gemm_o_f16<<<512, 256, 0, stream>>>(Yf, Wof, bo, out);
}